// Round 1
// baseline (62474.951 us; speedup 1.0000x reference)
//
#include <hip/hip_runtime.h>
#include <cstddef>
#include <cstdint>

#define kB 16
#define kT 1500
#define kF 80
#define kH 512
#define kGG 1024
#define kM (kB * kT)

// ---------------------------------------------------------------------------
// GEMM: C(M,1024) = A(M,K) @ Bt(1024,K)^T   (all row-major, fp32)
// 64x64 tile, 256 threads, 4x4 microtile, K staged in LDS 16 at a time.
// ---------------------------------------------------------------------------
__global__ __launch_bounds__(256) void gemm_nt_k(
    const float* __restrict__ A, const float* __restrict__ Bt,
    float* __restrict__ C, int K) {
  __shared__ float As[16][68];
  __shared__ float Bs[16][68];
  const int tid = threadIdx.x;
  const int m0 = blockIdx.x * 64;
  const int n0 = blockIdx.y * 64;
  const int tx = tid & 15;   // col group
  const int ty = tid >> 4;   // row group
  const int r  = tid >> 2;   // load row 0..63
  const int q  = tid & 3;    // load k-quad 0..3
  float acc[4][4] = {};
  for (int k0 = 0; k0 < K; k0 += 16) {
    const float4 va = *(const float4*)&A [(size_t)(m0 + r) * K + k0 + q * 4];
    const float4 vb = *(const float4*)&Bt[(size_t)(n0 + r) * K + k0 + q * 4];
    __syncthreads();
    As[q * 4 + 0][r] = va.x; As[q * 4 + 1][r] = va.y;
    As[q * 4 + 2][r] = va.z; As[q * 4 + 3][r] = va.w;
    Bs[q * 4 + 0][r] = vb.x; Bs[q * 4 + 1][r] = vb.y;
    Bs[q * 4 + 2][r] = vb.z; Bs[q * 4 + 3][r] = vb.w;
    __syncthreads();
#pragma unroll
    for (int kk = 0; kk < 16; ++kk) {
      const float4 a = *(const float4*)&As[kk][ty * 4];
      const float4 b = *(const float4*)&Bs[kk][tx * 4];
      acc[0][0] += a.x * b.x; acc[0][1] += a.x * b.y; acc[0][2] += a.x * b.z; acc[0][3] += a.x * b.w;
      acc[1][0] += a.y * b.x; acc[1][1] += a.y * b.y; acc[1][2] += a.y * b.z; acc[1][3] += a.y * b.w;
      acc[2][0] += a.z * b.x; acc[2][1] += a.z * b.y; acc[2][2] += a.z * b.z; acc[2][3] += a.z * b.w;
      acc[3][0] += a.w * b.x; acc[3][1] += a.w * b.y; acc[3][2] += a.w * b.z; acc[3][3] += a.w * b.w;
    }
  }
#pragma unroll
  for (int i = 0; i < 4; ++i) {
    float4 o;
    o.x = acc[i][0]; o.y = acc[i][1]; o.z = acc[i][2]; o.w = acc[i][3];
    *(float4*)&C[(size_t)(m0 + ty * 4 + i) * kGG + n0 + tx * 4] = o;
  }
}

// ---------------------------------------------------------------------------
// LayerNorm over rows of length 1024 (in place), y = (x-mu)*rsqrt(var+eps)*g+b
// One block (256 threads) per row.
// ---------------------------------------------------------------------------
__global__ __launch_bounds__(256) void ln_rows(
    float* __restrict__ w, const float* __restrict__ g,
    const float* __restrict__ bb) {
  const int row = blockIdx.x;
  float4* p = (float4*)(w + (size_t)row * kGG);
  const int tid = threadIdx.x;
  float4 v = p[tid];
  float s  = v.x + v.y + v.z + v.w;
  float s2 = v.x * v.x + v.y * v.y + v.z * v.z + v.w * v.w;
#pragma unroll
  for (int off = 32; off >= 1; off >>= 1) {
    s  += __shfl_down(s, off);
    s2 += __shfl_down(s2, off);
  }
  __shared__ float red[8];
  const int lane = tid & 63, wv = tid >> 6;
  if (lane == 0) { red[wv] = s; red[4 + wv] = s2; }
  __syncthreads();
  s  = red[0] + red[1] + red[2] + red[3];
  s2 = red[4] + red[5] + red[6] + red[7];
  const float mu  = s * (1.f / kGG);
  const float var = s2 * (1.f / kGG) - mu * mu;
  const float rs  = rsqrtf(var + 1e-5f);
  const float4 gg = ((const float4*)g)[tid];
  const float4 bv = ((const float4*)bb)[tid];
  v.x = (v.x - mu) * rs * gg.x + bv.x;
  v.y = (v.y - mu) * rs * gg.y + bv.y;
  v.z = (v.z - mu) * rs * gg.z + bv.z;
  v.w = (v.w - mu) * rs * gg.w + bv.w;
  p[tid] = v;
}

// ---------------------------------------------------------------------------
// LiGRU scan. Cooperative launch, 256 blocks x 256 threads.
// Block = (batch b = blk>>4, j-tile jblk = blk&15 owning 32 j's).
// Thread = (jj = tid>>3 in [0,32), ks = tid&7 K-split of 64 each).
// U rows (j and j+512, 64 K-elems each) live in registers for the whole scan.
// Per step: load h chunk, 128 FMAs, shuffle-reduce over 8 lanes, gate update,
// write h to the other h buffer + output, per-batch atomic barrier (16 blocks).
// ---------------------------------------------------------------------------
__global__ __launch_bounds__(256, 1) void ligru_scan(
    const float* __restrict__ wn,   // (B*T, 1024) normalized pre-gates
    const float* __restrict__ U,    // (1024, 512)
    float* __restrict__ hbuf,       // 2 * B * H (double buffered h state)
    float* __restrict__ out,        // (B*T, H)
    int* __restrict__ cnt) {        // 16 counters, stride 16 ints (64B)
  const int blk  = blockIdx.x;
  const int b    = blk >> 4;
  const int jblk = blk & 15;
  const int tid  = threadIdx.x;
  const int ks   = tid & 7;
  const int jj   = tid >> 3;
  const int j    = jblk * 32 + jj;
  const int k0   = ks * 64;

  // Preload this thread's U slice into registers (stays for all 1500 steps).
  float4 ua[16], uz[16];
#pragma unroll
  for (int q2 = 0; q2 < 16; ++q2) {
    ua[q2] = *(const float4*)&U[(size_t)j * kH + k0 + q2 * 4];
    uz[q2] = *(const float4*)&U[(size_t)(j + kH) * kH + k0 + q2 * 4];
  }

  float hprev = 0.f;                    // h[b,j], tracked by lane ks==0
  int* mycnt = cnt + b * 16;
  const float* wrow = wn + (size_t)b * kT * kGG;
  float* outp = out + (size_t)b * kT * kH + j;
  float* hb0 = hbuf + (size_t)b * kH;
  float* hb1 = hbuf + (size_t)(kB * kH) + (size_t)b * kH;

  for (int t = 0; t < kT; ++t) {
    const float* hsrc = ((t & 1) ? hb1 : hb0) + k0;
    float* hdst = (t & 1) ? hb0 : hb1;

    float4 hr[16];
#pragma unroll
    for (int q2 = 0; q2 < 16; ++q2) hr[q2] = *(const float4*)&hsrc[q2 * 4];

    float ga = 0.f, gz = 0.f;
#pragma unroll
    for (int q2 = 0; q2 < 16; ++q2) {
      ga += hr[q2].x * ua[q2].x; ga += hr[q2].y * ua[q2].y;
      ga += hr[q2].z * ua[q2].z; ga += hr[q2].w * ua[q2].w;
      gz += hr[q2].x * uz[q2].x; gz += hr[q2].y * uz[q2].y;
      gz += hr[q2].z * uz[q2].z; gz += hr[q2].w * uz[q2].w;
    }
#pragma unroll
    for (int off = 1; off < 8; off <<= 1) {
      ga += __shfl_xor(ga, off);
      gz += __shfl_xor(gz, off);
    }

    if (ks == 0) {
      const float a    = wrow[(size_t)t * kGG + j] + ga;
      const float z    = wrow[(size_t)t * kGG + j + kH] + gz;
      const float zt   = 1.f / (1.f + __expf(-z));
      const float hc   = fmaxf(a, 0.f);
      const float hnew = zt * hprev + (1.f - zt) * hc;
      hprev = hnew;
      hdst[j] = hnew;
      outp[(size_t)t * kH] = hnew;
    }

    __syncthreads();   // all reads of hsrc + writes of hdst issued & drained
    if (tid == 0) {
      __hip_atomic_fetch_add(mycnt, 1, __ATOMIC_RELEASE,
                             __HIP_MEMORY_SCOPE_AGENT);
      const int target = 16 * (t + 1);
      while (__hip_atomic_load(mycnt, __ATOMIC_RELAXED,
                               __HIP_MEMORY_SCOPE_AGENT) < target) {
        __builtin_amdgcn_s_sleep(1);
      }
    }
    __syncthreads();
    __threadfence();   // acquire: next step's h loads must see fresh data
  }
}

// ---------------------------------------------------------------------------
extern "C" void kernel_launch(void* const* d_in, const int* in_sizes, int n_in,
                              void* d_out, int out_size, void* d_ws,
                              size_t ws_size, hipStream_t stream) {
  const float* x  = (const float*)d_in[0];
  const float* W0 = (const float*)d_in[1];
  const float* U0 = (const float*)d_in[2];
  const float* g0 = (const float*)d_in[3];
  const float* b0 = (const float*)d_in[4];
  const float* W1 = (const float*)d_in[5];
  const float* U1 = (const float*)d_in[6];
  const float* g1 = (const float*)d_in[7];
  const float* b1 = (const float*)d_in[8];
  float* out = (float*)d_out;

  float* w    = (float*)d_ws;                       // 24000*1024 floats (98.3MB)
  float* hbuf = w + (size_t)kM * kGG;               // 2*16*512 floats (64KB)
  int*   cnt  = (int*)(hbuf + 2 * kB * kH);         // 512 ints (2KB)

  // zero h state + barrier counters (both layers' counter regions)
  hipMemsetAsync(hbuf, 0, (size_t)(2 * kB * kH) * sizeof(float) +
                              512 * sizeof(int), stream);

  // ---------------- layer 0 ----------------
  gemm_nt_k<<<dim3(kM / 64, kGG / 64), 256, 0, stream>>>(x, W0, w, kF);
  ln_rows<<<kM, 256, 0, stream>>>(w, g0, b0);
  {
    const float* wn_p = w;
    const float* U_p  = U0;
    float* hb_p = hbuf;
    float* out_p = out;
    int* cnt_p = cnt;
    void* args[] = {&wn_p, &U_p, &hb_p, &out_p, &cnt_p};
    hipLaunchCooperativeKernel((const void*)ligru_scan, dim3(256), dim3(256),
                               args, 0, stream);
  }

  // ---------------- layer 1 ----------------
  gemm_nt_k<<<dim3(kM / 64, kGG / 64), 256, 0, stream>>>(out, W1, w, kH);
  ln_rows<<<kM, 256, 0, stream>>>(w, g1, b1);
  hipMemsetAsync(hbuf, 0, (size_t)(2 * kB * kH) * sizeof(float), stream);
  {
    const float* wn_p = w;
    const float* U_p  = U1;
    float* hb_p = hbuf;
    float* out_p = out;
    int* cnt_p = cnt + 256;   // second counter region
    void* args[] = {&wn_p, &U_p, &hb_p, &out_p, &cnt_p};
    hipLaunchCooperativeKernel((const void*)ligru_scan, dim3(256), dim3(256),
                               args, 0, stream);
  }
}

// Round 2
// 5896.453 us; speedup vs baseline: 10.5953x; 10.5953x over previous
//
#include <hip/hip_runtime.h>
#include <cstddef>
#include <cstdint>

#define kB 16
#define kT 1500
#define kF 80
#define kH 512
#define kGG 1024
#define kM (kB * kT)

// ---------------------------------------------------------------------------
// GEMM: C(M,1024) = A(M,K) @ Bt(1024,K)^T   (all row-major, fp32)
// 64x64 tile, 256 threads, 4x4 microtile, K staged in LDS 16 at a time.
// ---------------------------------------------------------------------------
__global__ __launch_bounds__(256) void gemm_nt_k(
    const float* __restrict__ A, const float* __restrict__ Bt,
    float* __restrict__ C, int K) {
  __shared__ float As[16][68];
  __shared__ float Bs[16][68];
  const int tid = threadIdx.x;
  const int m0 = blockIdx.x * 64;
  const int n0 = blockIdx.y * 64;
  const int tx = tid & 15;   // col group
  const int ty = tid >> 4;   // row group
  const int r  = tid >> 2;   // load row 0..63
  const int q  = tid & 3;    // load k-quad 0..3
  float acc[4][4] = {};
  for (int k0 = 0; k0 < K; k0 += 16) {
    const float4 va = *(const float4*)&A [(size_t)(m0 + r) * K + k0 + q * 4];
    const float4 vb = *(const float4*)&Bt[(size_t)(n0 + r) * K + k0 + q * 4];
    __syncthreads();
    As[q * 4 + 0][r] = va.x; As[q * 4 + 1][r] = va.y;
    As[q * 4 + 2][r] = va.z; As[q * 4 + 3][r] = va.w;
    Bs[q * 4 + 0][r] = vb.x; Bs[q * 4 + 1][r] = vb.y;
    Bs[q * 4 + 2][r] = vb.z; Bs[q * 4 + 3][r] = vb.w;
    __syncthreads();
#pragma unroll
    for (int kk = 0; kk < 16; ++kk) {
      const float4 a = *(const float4*)&As[kk][ty * 4];
      const float4 b = *(const float4*)&Bs[kk][tx * 4];
      acc[0][0] += a.x * b.x; acc[0][1] += a.x * b.y; acc[0][2] += a.x * b.z; acc[0][3] += a.x * b.w;
      acc[1][0] += a.y * b.x; acc[1][1] += a.y * b.y; acc[1][2] += a.y * b.z; acc[1][3] += a.y * b.w;
      acc[2][0] += a.z * b.x; acc[2][1] += a.z * b.y; acc[2][2] += a.z * b.z; acc[2][3] += a.z * b.w;
      acc[3][0] += a.w * b.x; acc[3][1] += a.w * b.y; acc[3][2] += a.w * b.z; acc[3][3] += a.w * b.w;
    }
  }
#pragma unroll
  for (int i = 0; i < 4; ++i) {
    float4 o;
    o.x = acc[i][0]; o.y = acc[i][1]; o.z = acc[i][2]; o.w = acc[i][3];
    *(float4*)&C[(size_t)(m0 + ty * 4 + i) * kGG + n0 + tx * 4] = o;
  }
}

// ---------------------------------------------------------------------------
// LayerNorm over rows of length 1024 (in place)
// ---------------------------------------------------------------------------
__global__ __launch_bounds__(256) void ln_rows(
    float* __restrict__ w, const float* __restrict__ g,
    const float* __restrict__ bb) {
  const int row = blockIdx.x;
  float4* p = (float4*)(w + (size_t)row * kGG);
  const int tid = threadIdx.x;
  float4 v = p[tid];
  float s  = v.x + v.y + v.z + v.w;
  float s2 = v.x * v.x + v.y * v.y + v.z * v.z + v.w * v.w;
#pragma unroll
  for (int off = 32; off >= 1; off >>= 1) {
    s  += __shfl_down(s, off);
    s2 += __shfl_down(s2, off);
  }
  __shared__ float red[8];
  const int lane = tid & 63, wv = tid >> 6;
  if (lane == 0) { red[wv] = s; red[4 + wv] = s2; }
  __syncthreads();
  s  = red[0] + red[1] + red[2] + red[3];
  s2 = red[4] + red[5] + red[6] + red[7];
  const float mu  = s * (1.f / kGG);
  const float var = s2 * (1.f / kGG) - mu * mu;
  const float rs  = rsqrtf(var + 1e-5f);
  const float4 gg = ((const float4*)g)[tid];
  const float4 bv = ((const float4*)bb)[tid];
  v.x = (v.x - mu) * rs * gg.x + bv.x;
  v.y = (v.y - mu) * rs * gg.y + bv.y;
  v.z = (v.z - mu) * rs * gg.z + bv.z;
  v.w = (v.w - mu) * rs * gg.w + bv.w;
  p[tid] = v;
}

// ---------------------------------------------------------------------------
// LiGRU scan, barrier-free producer/consumer version.
// Invariant: h >= 0 always, so sign-bit-set == "not yet written" (hist is
// poisoned to 0xFFFFFFFF before launch). Producers publish h(t) words with
// relaxed agent-scope stores (write-through past non-coherent L2); consumers
// poll exactly the 2 words they own with relaxed agent-scope loads, then
// exchange the full 512-float h(t-1) via padded LDS (double-buffered, one
// __syncthreads per step, no global barrier, no fences).
//
// Block = (batch b = blk>>4, j-tile jblk = blk&15 owning 32 j's).
// Thread: jj = tid>>3 (output j within tile), ks = tid&7 (64-elem K-slice).
// U rows (j and j+512, 64 K-elems each) live in registers for all 1500 steps.
// ---------------------------------------------------------------------------
__global__ __launch_bounds__(256, 1) void ligru_scan(
    const float* __restrict__ wn,   // (B*T, 1024) normalized pre-gates
    const float* __restrict__ U,    // (1024, 512)
    float* __restrict__ hist) {     // (B, T, 512) h history == layer output
  const int blk  = blockIdx.x;
  const int b    = blk >> 4;
  const int jblk = blk & 15;
  const int tid  = threadIdx.x;
  const int ks   = tid & 7;
  const int jj   = tid >> 3;
  const int j    = jblk * 32 + jj;
  const int k0   = ks * 64;

  // chunk stride 68 floats: chunk c starts at bank 4c -> conflict-free reads
  __shared__ float hsh[2][8 * 68];

  float4 ua[16], uz[16];
#pragma unroll
  for (int q = 0; q < 16; ++q) {
    ua[q] = *(const float4*)&U[(size_t)j * kH + k0 + q * 4];
    uz[q] = *(const float4*)&U[(size_t)(j + kH) * kH + k0 + q * 4];
  }

  const float* wrow = wn + (size_t)b * kT * kGG;
  float* hrow = hist + (size_t)b * kT * kH;

  const int w0 = 2 * tid;                       // the 2 h-words this thread polls
  const int lc = (w0 >> 6) * 68 + (w0 & 63);    // their LDS slot

  float hprev = 0.f;   // h[b,j] carried by ks==0 lanes

  for (int t = 0; t < kT; ++t) {
    // prefetch this step's w values early (consumed after the dot product)
    float wa = 0.f, wz = 0.f;
    if (ks == 0) {
      wa = wrow[(size_t)t * kGG + j];
      wz = wrow[(size_t)t * kGG + kH + j];
    }

    float* dst = hsh[t & 1];
    if (t == 0) {
      *(float2*)&dst[lc] = make_float2(0.f, 0.f);
    } else {
      const int* hp = (const int*)(hrow + (size_t)(t - 1) * kH);
      int v0, v1;
      do {
        v0 = __hip_atomic_load(hp + w0,     __ATOMIC_RELAXED,
                               __HIP_MEMORY_SCOPE_AGENT);
        v1 = __hip_atomic_load(hp + w0 + 1, __ATOMIC_RELAXED,
                               __HIP_MEMORY_SCOPE_AGENT);
      } while ((v0 | v1) < 0);   // sign bit set on either => not ready
      *(float2*)&dst[lc] = make_float2(__int_as_float(v0), __int_as_float(v1));
    }
    __syncthreads();   // h(t-1) fully staged in LDS buffer t&1

    const float* src = dst + ks * 68;
    float ga = 0.f, gz = 0.f;
#pragma unroll
    for (int q = 0; q < 16; ++q) {
      const float4 h4 = *(const float4*)&src[q * 4];
      ga += h4.x * ua[q].x + h4.y * ua[q].y + h4.z * ua[q].z + h4.w * ua[q].w;
      gz += h4.x * uz[q].x + h4.y * uz[q].y + h4.z * uz[q].z + h4.w * uz[q].w;
    }
#pragma unroll
    for (int off = 1; off < 8; off <<= 1) {
      ga += __shfl_xor(ga, off);
      gz += __shfl_xor(gz, off);
    }

    if (ks == 0) {
      const float a    = wa + ga;
      const float z    = wz + gz;
      const float zt   = 1.f / (1.f + __expf(-z));
      const float hc   = fmaxf(a, 0.f);
      const float hnew = zt * hprev + (1.f - zt) * hc;
      hprev = hnew;
      __hip_atomic_store((int*)&hrow[(size_t)t * kH + j], __float_as_int(hnew),
                         __ATOMIC_RELAXED, __HIP_MEMORY_SCOPE_AGENT);
    }
    // no trailing barrier: next iteration writes the OTHER LDS buffer, and
    // the next __syncthreads orders those writes vs this step's reads.
  }
}

// ---------------------------------------------------------------------------
extern "C" void kernel_launch(void* const* d_in, const int* in_sizes, int n_in,
                              void* d_out, int out_size, void* d_ws,
                              size_t ws_size, hipStream_t stream) {
  const float* x  = (const float*)d_in[0];
  const float* W0 = (const float*)d_in[1];
  const float* U0 = (const float*)d_in[2];
  const float* g0 = (const float*)d_in[3];
  const float* b0 = (const float*)d_in[4];
  const float* W1 = (const float*)d_in[5];
  const float* U1 = (const float*)d_in[6];
  const float* g1 = (const float*)d_in[7];
  const float* b1 = (const float*)d_in[8];
  float* out = (float*)d_out;

  float* w = (float*)d_ws;   // 24000*1024 floats (98.3MB)

  const size_t out_bytes = (size_t)kM * kH * sizeof(float);   // 49.2MB

  // ---------------- layer 0 ----------------
  hipMemsetAsync(out, 0xFF, out_bytes, stream);   // poison = "not ready"
  gemm_nt_k<<<dim3(kM / 64, kGG / 64), 256, 0, stream>>>(x, W0, w, kF);
  ln_rows<<<kM, 256, 0, stream>>>(w, g0, b0);
  {
    const float* wn_p = w;
    const float* U_p  = U0;
    float* h_p = out;                 // layer-0 h history == GEMM2 input
    void* args[] = {&wn_p, &U_p, &h_p};
    hipLaunchCooperativeKernel((const void*)ligru_scan, dim3(256), dim3(256),
                               args, 0, stream);
  }

  // ---------------- layer 1 ----------------
  gemm_nt_k<<<dim3(kM / 64, kGG / 64), 256, 0, stream>>>(out, W1, w, kH);
  ln_rows<<<kM, 256, 0, stream>>>(w, g1, b1);
  hipMemsetAsync(out, 0xFF, out_bytes, stream);   // re-poison for layer 1
  {
    const float* wn_p = w;
    const float* U_p  = U1;
    float* h_p = out;                 // final output
    void* args[] = {&wn_p, &U_p, &h_p};
    hipLaunchCooperativeKernel((const void*)ligru_scan, dim3(256), dim3(256),
                               args, 0, stream);
  }
}

// Round 3
// 5033.451 us; speedup vs baseline: 12.4120x; 1.1715x over previous
//
#include <hip/hip_runtime.h>
#include <cstddef>
#include <cstdint>

#define kB 16
#define kT 1500
#define kF 80
#define kH 512
#define kGG 1024
#define kM (kB * kT)

typedef int v2i __attribute__((ext_vector_type(2)));

// Two-word poll load. deep=false: sc0 only (L1-bypass, can hit own-XCD L2 —
// fast path when producer is colocated and its write-through updates L2).
// deep=true: sc0 sc1 (bypass L2, read LLC truth — guarantees progress
// regardless of block->XCD placement).
__device__ __forceinline__ v2i poll_ld(const int* p, bool deep) {
  v2i v;
  if (deep)
    asm volatile("global_load_dwordx2 %0, %1, off sc0 sc1\n\t"
                 "s_waitcnt vmcnt(0)"
                 : "=v"(v) : "v"(p) : "memory");
  else
    asm volatile("global_load_dwordx2 %0, %1, off sc0\n\t"
                 "s_waitcnt vmcnt(0)"
                 : "=v"(v) : "v"(p) : "memory");
  return v;
}

// ---------------------------------------------------------------------------
// GEMM: C(M,1024) = A(M,K) @ Bt(1024,K)^T   (all row-major, fp32)
// ---------------------------------------------------------------------------
__global__ __launch_bounds__(256) void gemm_nt_k(
    const float* __restrict__ A, const float* __restrict__ Bt,
    float* __restrict__ C, int K) {
  __shared__ float As[16][68];
  __shared__ float Bs[16][68];
  const int tid = threadIdx.x;
  const int m0 = blockIdx.x * 64;
  const int n0 = blockIdx.y * 64;
  const int tx = tid & 15;
  const int ty = tid >> 4;
  const int r  = tid >> 2;
  const int q  = tid & 3;
  float acc[4][4] = {};
  for (int k0 = 0; k0 < K; k0 += 16) {
    const float4 va = *(const float4*)&A [(size_t)(m0 + r) * K + k0 + q * 4];
    const float4 vb = *(const float4*)&Bt[(size_t)(n0 + r) * K + k0 + q * 4];
    __syncthreads();
    As[q * 4 + 0][r] = va.x; As[q * 4 + 1][r] = va.y;
    As[q * 4 + 2][r] = va.z; As[q * 4 + 3][r] = va.w;
    Bs[q * 4 + 0][r] = vb.x; Bs[q * 4 + 1][r] = vb.y;
    Bs[q * 4 + 2][r] = vb.z; Bs[q * 4 + 3][r] = vb.w;
    __syncthreads();
#pragma unroll
    for (int kk = 0; kk < 16; ++kk) {
      const float4 a = *(const float4*)&As[kk][ty * 4];
      const float4 b = *(const float4*)&Bs[kk][tx * 4];
      acc[0][0] += a.x * b.x; acc[0][1] += a.x * b.y; acc[0][2] += a.x * b.z; acc[0][3] += a.x * b.w;
      acc[1][0] += a.y * b.x; acc[1][1] += a.y * b.y; acc[1][2] += a.y * b.z; acc[1][3] += a.y * b.w;
      acc[2][0] += a.z * b.x; acc[2][1] += a.z * b.y; acc[2][2] += a.z * b.z; acc[2][3] += a.z * b.w;
      acc[3][0] += a.w * b.x; acc[3][1] += a.w * b.y; acc[3][2] += a.w * b.z; acc[3][3] += a.w * b.w;
    }
  }
#pragma unroll
  for (int i = 0; i < 4; ++i) {
    float4 o;
    o.x = acc[i][0]; o.y = acc[i][1]; o.z = acc[i][2]; o.w = acc[i][3];
    *(float4*)&C[(size_t)(m0 + ty * 4 + i) * kGG + n0 + tx * 4] = o;
  }
}

// ---------------------------------------------------------------------------
// LayerNorm over rows of length 1024 (in place)
// ---------------------------------------------------------------------------
__global__ __launch_bounds__(256) void ln_rows(
    float* __restrict__ w, const float* __restrict__ g,
    const float* __restrict__ bb) {
  const int row = blockIdx.x;
  float4* p = (float4*)(w + (size_t)row * kGG);
  const int tid = threadIdx.x;
  float4 v = p[tid];
  float s  = v.x + v.y + v.z + v.w;
  float s2 = v.x * v.x + v.y * v.y + v.z * v.z + v.w * v.w;
#pragma unroll
  for (int off = 32; off >= 1; off >>= 1) {
    s  += __shfl_down(s, off);
    s2 += __shfl_down(s2, off);
  }
  __shared__ float red[8];
  const int lane = tid & 63, wv = tid >> 6;
  if (lane == 0) { red[wv] = s; red[4 + wv] = s2; }
  __syncthreads();
  s  = red[0] + red[1] + red[2] + red[3];
  s2 = red[4] + red[5] + red[6] + red[7];
  const float mu  = s * (1.f / kGG);
  const float var = s2 * (1.f / kGG) - mu * mu;
  const float rs  = rsqrtf(var + 1e-5f);
  const float4 gg = ((const float4*)g)[tid];
  const float4 bv = ((const float4*)bb)[tid];
  v.x = (v.x - mu) * rs * gg.x + bv.x;
  v.y = (v.y - mu) * rs * gg.y + bv.y;
  v.z = (v.z - mu) * rs * gg.z + bv.z;
  v.w = (v.w - mu) * rs * gg.w + bv.w;
  p[tid] = v;
}

// ---------------------------------------------------------------------------
// LiGRU scan, barrier-free producer/consumer.
// h >= 0 invariant => sign-bit-set == "not yet written" (hist poisoned 0xFF).
// Block decode: b = blk & 15  =>  batch b's 16 blocks are all == b (mod 8)
// => same XCD under round-robin dispatch (perf heuristic only; correctness
// does not depend on it thanks to the deep sc1 poll fallback).
// U slice is pinned in VGPRs via opaque asm (compiler cannot sink reloads).
// ---------------------------------------------------------------------------
__global__ __launch_bounds__(256, 1) void ligru_scan(
    const float* __restrict__ wn,   // (B*T, 1024) normalized pre-gates
    const float* __restrict__ U,    // (1024, 512)
    float* __restrict__ hist) {     // (B, T, 512) h history == layer output
  const int blk  = blockIdx.x;
  const int b    = blk & 15;     // XCD-colocating decode
  const int jblk = blk >> 4;
  const int tid  = threadIdx.x;
  const int ks   = tid & 7;
  const int jj   = tid >> 3;
  const int j    = jblk * 32 + jj;
  const int k0   = ks * 64;

  // chunk stride 68 floats -> conflict-free b128 reads
  __shared__ float hsh[2][8 * 68];

  float4 ua[16], uz[16];
#pragma unroll
  for (int q = 0; q < 16; ++q) {
    ua[q] = *(const float4*)&U[(size_t)j * kH + k0 + q * 4];
    uz[q] = *(const float4*)&U[(size_t)(j + kH) * kH + k0 + q * 4];
    // Pin in VGPRs: opaque to the optimizer, cannot be rematerialized.
    asm volatile("" : "+v"(ua[q].x), "+v"(ua[q].y), "+v"(ua[q].z), "+v"(ua[q].w));
    asm volatile("" : "+v"(uz[q].x), "+v"(uz[q].y), "+v"(uz[q].z), "+v"(uz[q].w));
  }

  const float* wrow = wn + (size_t)b * kT * kGG;
  float* hrow = hist + (size_t)b * kT * kH;

  const int w0 = 2 * tid;                     // 2 h-words this thread polls
  const int lc = (w0 >> 6) * 68 + (w0 & 63);  // their LDS slot

  float hprev = 0.f;   // h[b,j], carried by ks==0 lanes

  for (int t = 0; t < kT; ++t) {
    // prefetch this step's w values (latency overlaps the poll below)
    float wa = 0.f, wz = 0.f;
    if (ks == 0) {
      wa = wrow[(size_t)t * kGG + j];
      wz = wrow[(size_t)t * kGG + kH + j];
    }

    float* dst = hsh[t & 1];
    if (t == 0) {
      *(float2*)&dst[lc] = make_float2(0.f, 0.f);
    } else {
      const int* hp = (const int*)(hrow + (size_t)(t - 1) * kH) + w0;
      v2i v = poll_ld(hp, false);
      int spins = 0;
      while ((v.x | v.y) < 0) {
        ++spins;
        v = poll_ld(hp, (spins & 1) != 0);   // alternate sc0 / sc0+sc1
      }
      *(float2*)&dst[lc] = make_float2(__int_as_float(v.x), __int_as_float(v.y));
    }
    __syncthreads();   // h(t-1) staged in LDS buffer t&1

    const float* src = dst + ks * 68;
    float ga = 0.f, gz = 0.f;
#pragma unroll
    for (int q = 0; q < 16; ++q) {
      const float4 h4 = *(const float4*)&src[q * 4];
      ga += h4.x * ua[q].x + h4.y * ua[q].y + h4.z * ua[q].z + h4.w * ua[q].w;
      gz += h4.x * uz[q].x + h4.y * uz[q].y + h4.z * uz[q].z + h4.w * uz[q].w;
    }
#pragma unroll
    for (int off = 1; off < 8; off <<= 1) {
      ga += __shfl_xor(ga, off);
      gz += __shfl_xor(gz, off);
    }

    if (ks == 0) {
      const float a    = wa + ga;
      const float z    = wz + gz;
      const float zt   = 1.f / (1.f + __expf(-z));
      const float hc   = fmaxf(a, 0.f);
      const float hnew = zt * hprev + (1.f - zt) * hc;
      hprev = hnew;
      // agent-scope write-through: always LLC-visible (placement-independent)
      __hip_atomic_store((int*)&hrow[(size_t)t * kH + j], __float_as_int(hnew),
                         __ATOMIC_RELAXED, __HIP_MEMORY_SCOPE_AGENT);
    }
    // next iteration uses the other LDS buffer; its __syncthreads orders
    // those writes against this step's reads.
  }
}

// ---------------------------------------------------------------------------
extern "C" void kernel_launch(void* const* d_in, const int* in_sizes, int n_in,
                              void* d_out, int out_size, void* d_ws,
                              size_t ws_size, hipStream_t stream) {
  const float* x  = (const float*)d_in[0];
  const float* W0 = (const float*)d_in[1];
  const float* U0 = (const float*)d_in[2];
  const float* g0 = (const float*)d_in[3];
  const float* b0 = (const float*)d_in[4];
  const float* W1 = (const float*)d_in[5];
  const float* U1 = (const float*)d_in[6];
  const float* g1 = (const float*)d_in[7];
  const float* b1 = (const float*)d_in[8];
  float* out = (float*)d_out;

  float* w = (float*)d_ws;   // 24000*1024 floats (98.3MB)

  const size_t out_bytes = (size_t)kM * kH * sizeof(float);   // 49.2MB

  // ---------------- layer 0 ----------------
  hipMemsetAsync(out, 0xFF, out_bytes, stream);   // poison = "not ready"
  gemm_nt_k<<<dim3(kM / 64, kGG / 64), 256, 0, stream>>>(x, W0, w, kF);
  ln_rows<<<kM, 256, 0, stream>>>(w, g0, b0);
  {
    const float* wn_p = w;
    const float* U_p  = U0;
    float* h_p = out;                 // layer-0 h history == GEMM2 input
    void* args[] = {&wn_p, &U_p, &h_p};
    hipLaunchCooperativeKernel((const void*)ligru_scan, dim3(256), dim3(256),
                               args, 0, stream);
  }

  // ---------------- layer 1 ----------------
  gemm_nt_k<<<dim3(kM / 64, kGG / 64), 256, 0, stream>>>(out, W1, w, kH);
  ln_rows<<<kM, 256, 0, stream>>>(w, g1, b1);
  hipMemsetAsync(out, 0xFF, out_bytes, stream);   // re-poison for layer 1
  {
    const float* wn_p = w;
    const float* U_p  = U1;
    float* h_p = out;                 // final output
    void* args[] = {&wn_p, &U_p, &h_p};
    hipLaunchCooperativeKernel((const void*)ligru_scan, dim3(256), dim3(256),
                               args, 0, stream);
  }
}

// Round 5
// 4892.582 us; speedup vs baseline: 12.7693x; 1.0288x over previous
//
#include <hip/hip_runtime.h>
#include <cstddef>
#include <cstdint>

#define kB 16
#define kT 1500
#define kF 80
#define kH 512
#define kGG 1024
#define kM (kB * kT)

typedef int v4i __attribute__((ext_vector_type(4)));

// Deep poll, split issue/wait. sc0 sc1 = system scope: bypasses L1+L2, reads
// LLC truth — guaranteed progress regardless of block->XCD placement.
__device__ __forceinline__ void poll_issue(const int* p, v4i* v) {
  asm volatile("global_load_dwordx4 %0, %1, off sc0 sc1"
               : "=v"(*v) : "v"(p) : "memory");
}
__device__ __forceinline__ void poll_wait(v4i* v) {
  asm volatile("s_waitcnt vmcnt(0)" : "+v"(*v) :: "memory");
}

// ---------------------------------------------------------------------------
// GEMM: C(M,1024) = A(M,K) @ Bt(1024,K)^T   (all row-major, fp32)
// ---------------------------------------------------------------------------
__global__ __launch_bounds__(256) void gemm_nt_k(
    const float* __restrict__ A, const float* __restrict__ Bt,
    float* __restrict__ C, int K) {
  __shared__ float As[16][68];
  __shared__ float Bs[16][68];
  const int tid = threadIdx.x;
  const int m0 = blockIdx.x * 64;
  const int n0 = blockIdx.y * 64;
  const int tx = tid & 15;
  const int ty = tid >> 4;
  const int r  = tid >> 2;
  const int q  = tid & 3;
  float acc[4][4] = {};
  for (int k0 = 0; k0 < K; k0 += 16) {
    const float4 va = *(const float4*)&A [(size_t)(m0 + r) * K + k0 + q * 4];
    const float4 vb = *(const float4*)&Bt[(size_t)(n0 + r) * K + k0 + q * 4];
    __syncthreads();
    As[q * 4 + 0][r] = va.x; As[q * 4 + 1][r] = va.y;
    As[q * 4 + 2][r] = va.z; As[q * 4 + 3][r] = va.w;
    Bs[q * 4 + 0][r] = vb.x; Bs[q * 4 + 1][r] = vb.y;
    Bs[q * 4 + 2][r] = vb.z; Bs[q * 4 + 3][r] = vb.w;
    __syncthreads();
#pragma unroll
    for (int kk = 0; kk < 16; ++kk) {
      const float4 a = *(const float4*)&As[kk][ty * 4];
      const float4 b = *(const float4*)&Bs[kk][tx * 4];
      acc[0][0] += a.x * b.x; acc[0][1] += a.x * b.y; acc[0][2] += a.x * b.z; acc[0][3] += a.x * b.w;
      acc[1][0] += a.y * b.x; acc[1][1] += a.y * b.y; acc[1][2] += a.y * b.z; acc[1][3] += a.y * b.w;
      acc[2][0] += a.z * b.x; acc[2][1] += a.z * b.y; acc[2][2] += a.z * b.z; acc[2][3] += a.z * b.w;
      acc[3][0] += a.w * b.x; acc[3][1] += a.w * b.y; acc[3][2] += a.w * b.z; acc[3][3] += a.w * b.w;
    }
  }
#pragma unroll
  for (int i = 0; i < 4; ++i) {
    float4 o;
    o.x = acc[i][0]; o.y = acc[i][1]; o.z = acc[i][2]; o.w = acc[i][3];
    *(float4*)&C[(size_t)(m0 + ty * 4 + i) * kGG + n0 + tx * 4] = o;
  }
}

// ---------------------------------------------------------------------------
// LayerNorm over rows of length 1024 (in place)
// ---------------------------------------------------------------------------
__global__ __launch_bounds__(256) void ln_rows(
    float* __restrict__ w, const float* __restrict__ g,
    const float* __restrict__ bb) {
  const int row = blockIdx.x;
  float4* p = (float4*)(w + (size_t)row * kGG);
  const int tid = threadIdx.x;
  float4 v = p[tid];
  float s  = v.x + v.y + v.z + v.w;
  float s2 = v.x * v.x + v.y * v.y + v.z * v.z + v.w * v.w;
#pragma unroll
  for (int off = 32; off >= 1; off >>= 1) {
    s  += __shfl_down(s, off);
    s2 += __shfl_down(s2, off);
  }
  __shared__ float red[8];
  const int lane = tid & 63, wv = tid >> 6;
  if (lane == 0) { red[wv] = s; red[4 + wv] = s2; }
  __syncthreads();
  s  = red[0] + red[1] + red[2] + red[3];
  s2 = red[4] + red[5] + red[6] + red[7];
  const float mu  = s * (1.f / kGG);
  const float var = s2 * (1.f / kGG) - mu * mu;
  const float rs  = rsqrtf(var + 1e-5f);
  const float4 gg = ((const float4*)g)[tid];
  const float4 bv = ((const float4*)bb)[tid];
  v.x = (v.x - mu) * rs * gg.x + bv.x;
  v.y = (v.y - mu) * rs * gg.y + bv.y;
  v.z = (v.z - mu) * rs * gg.z + bv.z;
  v.w = (v.w - mu) * rs * gg.w + bv.w;
  p[tid] = v;
}

// ---------------------------------------------------------------------------
// LiGRU scan, barrier-free producer/consumer (round-3 skeleton, tightened).
// h >= 0 invariant => sign-bit-set == "not yet written" (hist poisoned 0xFF).
// Producers: agent-scope relaxed stores (always LLC-visible).
// Consumers: 128 poller threads, one dwordx4 system-scope poll each (sc0 sc1,
// LLC truth — placement-independent), staged to padded LDS, one syncthreads.
// U slice pinned in VGPRs/AGPRs via opaque asm.
// ---------------------------------------------------------------------------
__global__ __launch_bounds__(256, 1) void ligru_scan(
    const float* __restrict__ wn,   // (B*T, 1024) normalized pre-gates
    const float* __restrict__ U,    // (1024, 512)
    float* __restrict__ hist) {     // (B, T, 512) h history == layer output
  const int blk  = blockIdx.x;
  const int b    = blk & 15;     // XCD-colocating decode (heuristic only)
  const int jblk = blk >> 4;
  const int tid  = threadIdx.x;
  const int ks   = tid & 7;
  const int jj   = tid >> 3;
  const int j    = jblk * 32 + jj;
  const int k0   = ks * 64;

  __shared__ float hsh[2][8 * 68];   // stride 68 -> conflict-free b128 reads

  // ---- U slice pinned in registers ----
  float4 ua[16], uz[16];
#pragma unroll
  for (int q = 0; q < 16; ++q) {
    ua[q] = *(const float4*)&U[(size_t)j * kH + k0 + q * 4];
    uz[q] = *(const float4*)&U[(size_t)(j + kH) * kH + k0 + q * 4];
    asm volatile("" : "+v"(ua[q].x), "+v"(ua[q].y), "+v"(ua[q].z), "+v"(ua[q].w));
    asm volatile("" : "+v"(uz[q].x), "+v"(uz[q].y), "+v"(uz[q].z), "+v"(uz[q].w));
  }

  const float* wrow = wn + (size_t)b * kT * kGG;
  float* hrow = hist + (size_t)b * kT * kH;

  const bool poller = (tid < 128);
  const int w0 = 4 * tid;                      // 4 h-words each poller owns
  const int lc = (w0 >> 6) * 68 + (w0 & 63);   // their LDS slot (float4-safe)

  float hprev = 0.f;   // h[b,j], carried by ks==0 lanes

  for (int t = 0; t < kT; ++t) {
    float* dst = hsh[t & 1];
    if (poller) {
      if (t == 0) {
        *(float4*)&dst[lc] = make_float4(0.f, 0.f, 0.f, 0.f);
      } else {
        const int* hp = (const int*)(hrow + (size_t)(t - 1) * kH) + w0;
        v4i v;
        poll_issue(hp, &v);
        poll_wait(&v);
        while ((v.x | v.y | v.z | v.w) < 0) {   // any sign bit set => retry
          poll_issue(hp, &v);
          poll_wait(&v);
        }
        float4 f;
        f.x = __int_as_float(v.x); f.y = __int_as_float(v.y);
        f.z = __int_as_float(v.z); f.w = __int_as_float(v.w);
        *(float4*)&dst[lc] = f;
      }
    }
    __syncthreads();   // h(t-1) staged in LDS buffer t&1

    // w prefetch AFTER the poll (so poll's vmcnt(0) never drains it);
    // its latency hides under the dot below (compiler waits at use).
    float wa = 0.f, wz = 0.f;
    if (ks == 0) {
      wa = wrow[(size_t)t * kGG + j];
      wz = wrow[(size_t)t * kGG + kH + j];
    }

    const float* src = dst + ks * 68;
    float ga = 0.f, gz = 0.f;
#pragma unroll
    for (int q = 0; q < 16; ++q) {
      const float4 h4 = *(const float4*)&src[q * 4];
      ga += h4.x * ua[q].x + h4.y * ua[q].y + h4.z * ua[q].z + h4.w * ua[q].w;
      gz += h4.x * uz[q].x + h4.y * uz[q].y + h4.z * uz[q].z + h4.w * uz[q].w;
    }
#pragma unroll
    for (int off = 1; off < 8; off <<= 1) {
      ga += __shfl_xor(ga, off);
      gz += __shfl_xor(gz, off);
    }

    if (ks == 0) {
      const float a    = wa + ga;
      const float z    = wz + gz;
      const float zt   = 1.f / (1.f + __expf(-z));
      const float hc   = fmaxf(a, 0.f);
      const float hnew = zt * hprev + (1.f - zt) * hc;
      hprev = hnew;
      // agent-scope write-through: LLC-visible, placement-independent
      __hip_atomic_store((int*)&hrow[(size_t)t * kH + j], __float_as_int(hnew),
                         __ATOMIC_RELAXED, __HIP_MEMORY_SCOPE_AGENT);
    }
    // next iteration uses the other LDS buffer; its __syncthreads orders
    // those writes against this step's reads.
  }
}

// ---------------------------------------------------------------------------
extern "C" void kernel_launch(void* const* d_in, const int* in_sizes, int n_in,
                              void* d_out, int out_size, void* d_ws,
                              size_t ws_size, hipStream_t stream) {
  const float* x  = (const float*)d_in[0];
  const float* W0 = (const float*)d_in[1];
  const float* U0 = (const float*)d_in[2];
  const float* g0 = (const float*)d_in[3];
  const float* b0 = (const float*)d_in[4];
  const float* W1 = (const float*)d_in[5];
  const float* U1 = (const float*)d_in[6];
  const float* g1 = (const float*)d_in[7];
  const float* b1 = (const float*)d_in[8];
  float* out = (float*)d_out;

  float* w = (float*)d_ws;   // 24000*1024 floats (98.3MB)

  const size_t out_bytes = (size_t)kM * kH * sizeof(float);   // 49.2MB

  // ---------------- layer 0 ----------------
  hipMemsetAsync(out, 0xFF, out_bytes, stream);   // poison = "not ready"
  gemm_nt_k<<<dim3(kM / 64, kGG / 64), 256, 0, stream>>>(x, W0, w, kF);
  ln_rows<<<kM, 256, 0, stream>>>(w, g0, b0);
  {
    const float* wn_p = w;
    const float* U_p  = U0;
    float* h_p = out;                 // layer-0 h history == GEMM2 input
    void* args[] = {&wn_p, &U_p, &h_p};
    hipLaunchCooperativeKernel((const void*)ligru_scan, dim3(256), dim3(256),
                               args, 0, stream);
  }

  // ---------------- layer 1 ----------------
  gemm_nt_k<<<dim3(kM / 64, kGG / 64), 256, 0, stream>>>(out, W1, w, kH);
  ln_rows<<<kM, 256, 0, stream>>>(w, g1, b1);
  hipMemsetAsync(out, 0xFF, out_bytes, stream);   // re-poison for layer 1
  {
    const float* wn_p = w;
    const float* U_p  = U1;
    float* h_p = out;                 // final output
    void* args[] = {&wn_p, &U_p, &h_p};
    hipLaunchCooperativeKernel((const void*)ligru_scan, dim3(256), dim3(256),
                               args, 0, stream);
  }
}